// Round 4
// baseline (134.159 us; speedup 1.0000x reference)
//
#include <hip/hip_runtime.h>
#include <hip/hip_bf16.h>
#include <float.h>
#include <math.h>

// BatchHardTripletLoss on MI355X — bf16x3 MFMA gram, depth-1 async pipeline,
// fused finalize (last-block-done). 2 launches total.
// batch = concat(h1,h2) : [4096,512] fp32 -> hi/lo bf16 split.
// dot(a,b) ~= hi.hi + hi.lo + lo.hi (fp32 MFMA accum) — validated exact in R3.

#define NTOT 4096
#define NHALF 2048
#define DIM 512
#define BM 128
#define BKE 32                         // k-elems staged per step
#define KSTEPS (DIM / BKE)             // 16
#define NTILE (NTOT / BM)              // 32
#define NTRI (NTILE * (NTILE + 1) / 2) // 528
#define FLTMAX 3.402823466e+38f
#define ROW_USH 64                     // 128 B per row-entry: [hi 4x16B | lo 4x16B]
#define PHASE_USH (256 * ROW_USH)      // 256 rows (128 A + 128 B) = 32 KB

typedef __attribute__((ext_vector_type(8))) short bf16x8;
typedef __attribute__((ext_vector_type(4))) float f32x4;

#define GLLDS(gp, lp) __builtin_amdgcn_global_load_lds(                              \
    (const __attribute__((address_space(1))) void*)(gp),                             \
    (__attribute__((address_space(3))) void*)(lp), 16, 0, 0)

__device__ __forceinline__ ushort bf16hi_bits(float x, float* hf) {
    __hip_bfloat16 b = __float2bfloat16(x);
    *hf = __bfloat162float(b);
    return *reinterpret_cast<ushort*>(&b);
}
__device__ __forceinline__ ushort bf16_bits(float x) {
    __hip_bfloat16 b = __float2bfloat16(x);
    return *reinterpret_cast<ushort*>(&b);
}

// One wave per row-pair i: sq, exact partner d2, hi/lo split, minb init, cnt zero.
__global__ __launch_bounds__(256) void prep_kernel(const float* __restrict__ h1,
                                                   const float* __restrict__ h2,
                                                   float* __restrict__ sq,
                                                   float* __restrict__ hp_d2,
                                                   unsigned int* __restrict__ minb,
                                                   unsigned int* __restrict__ cnt,
                                                   ushort* __restrict__ hi,
                                                   ushort* __restrict__ lo) {
    if (blockIdx.x == 0 && threadIdx.x == 0) *cnt = 0u;
    int wv = threadIdx.x >> 6, lane = threadIdx.x & 63;
    int i = blockIdx.x * 4 + wv;
    if (i >= NHALF) return;
    if (lane < 2) minb[i + lane * NHALF] = 0x7F800000u;  // +inf bits

    const float4* r1 = (const float4*)(h1 + (size_t)i * DIM);
    const float4* r2 = (const float4*)(h2 + (size_t)i * DIM);
    float4 a0 = r1[lane], a1 = r1[lane + 64];
    float4 b0 = r2[lane], b1 = r2[lane + 64];

    float s1 = a0.x*a0.x + a0.y*a0.y + a0.z*a0.z + a0.w*a0.w
             + a1.x*a1.x + a1.y*a1.y + a1.z*a1.z + a1.w*a1.w;
    float s2 = b0.x*b0.x + b0.y*b0.y + b0.z*b0.z + b0.w*b0.w
             + b1.x*b1.x + b1.y*b1.y + b1.z*b1.z + b1.w*b1.w;
    float s12 = a0.x*b0.x + a0.y*b0.y + a0.z*b0.z + a0.w*b0.w
              + a1.x*b1.x + a1.y*b1.y + a1.z*b1.z + a1.w*b1.w;

    {
        float f[8] = {a0.x, a0.y, a0.z, a0.w, a1.x, a1.y, a1.z, a1.w};
        float g[8] = {b0.x, b0.y, b0.z, b0.w, b1.x, b1.y, b1.z, b1.w};
        ushort4 h4, l4v; float hf;
        #pragma unroll
        for (int half = 0; half < 2; ++half) {
            float* p = f + half * 4;
            h4.x = bf16hi_bits(p[0], &hf); l4v.x = bf16_bits(p[0] - hf);
            h4.y = bf16hi_bits(p[1], &hf); l4v.y = bf16_bits(p[1] - hf);
            h4.z = bf16hi_bits(p[2], &hf); l4v.z = bf16_bits(p[2] - hf);
            h4.w = bf16hi_bits(p[3], &hf); l4v.w = bf16_bits(p[3] - hf);
            size_t off = (size_t)i * DIM + half * 256 + lane * 4;
            *(ushort4*)(hi + off) = h4;
            *(ushort4*)(lo + off) = l4v;
        }
        #pragma unroll
        for (int half = 0; half < 2; ++half) {
            float* p = g + half * 4;
            h4.x = bf16hi_bits(p[0], &hf); l4v.x = bf16_bits(p[0] - hf);
            h4.y = bf16hi_bits(p[1], &hf); l4v.y = bf16_bits(p[1] - hf);
            h4.z = bf16hi_bits(p[2], &hf); l4v.z = bf16_bits(p[2] - hf);
            h4.w = bf16hi_bits(p[3], &hf); l4v.w = bf16_bits(p[3] - hf);
            size_t off = (size_t)(i + NHALF) * DIM + half * 256 + lane * 4;
            *(ushort4*)(hi + off) = h4;
            *(ushort4*)(lo + off) = l4v;
        }
    }

    #pragma unroll
    for (int m = 1; m < 64; m <<= 1) {
        s1  += __shfl_xor(s1, m);
        s2  += __shfl_xor(s2, m);
        s12 += __shfl_xor(s12, m);
    }
    if (lane == 0) {
        sq[i] = s1;
        sq[i + NHALF] = s2;
        float pd = s1 + s2 - 2.0f * s12;
        hp_d2[i] = pd;
        hp_d2[i + NHALF] = pd;
    }
}

// 528 triangular 128x128 tiles; 4 waves (2x2), wave tile 64x64 (4x4 frags of
// 16x16x32, 3 MFMA each). LDS: 2 phases x [256 rows][hi|lo 8x16B slots] = 64 KB,
// XOR-(row&7) slot swizzle, linear GLLDS dest + pre-swizzled per-lane source.
// Depth-1 pipeline: stage kt+1 before computing kt; one barrier per kt.
// Last finished block performs the final reduction (cnt in ws, zeroed by prep).
__global__ __launch_bounds__(256, 2) void pairmin_mfma(const ushort* __restrict__ hi,
                                                       const ushort* __restrict__ lo,
                                                       const float* __restrict__ sq,
                                                       const float* __restrict__ hp_d2,
                                                       unsigned int* __restrict__ minb,
                                                       unsigned int* __restrict__ cnt,
                                                       float* __restrict__ out) {
    __shared__ ushort lds[2 * PHASE_USH] __attribute__((aligned(16)));
    __shared__ unsigned int finflag;

    int t = blockIdx.x, bi = 0, rem = NTILE;
    while (t >= rem) { t -= rem; ++bi; --rem; }
    int bj = bi + t;
    int rowA0 = bi * BM, rowB0 = bj * BM;

    int tid = threadIdx.x;
    int w = tid >> 6, lane = tid & 63;
    int wr = w >> 1, wc = w & 1;
    int l15 = lane & 15, l4 = lane >> 4;

    // Per-lane stage sources: 8 GLLDS/wave, each 1 KB of LDS (8 rows x 128 B).
    // LDS[row][c] holds global chunk c ^ (row&7); chunks 0-3 = hi, 4-7 = lo.
    int rloc = lane >> 3, ccol = lane & 7;
    int sg = ccol ^ rloc;
    const ushort* sbase = (sg & 4) ? lo : hi;
    int sc = sg & 3;
    const ushort* srcp[8];
    #pragma unroll
    for (int j = 0; j < 8; ++j) {
        int brow = w * 64 + j * 8 + rloc;                  // 0..255
        int grow = (brow < BM) ? (rowA0 + brow) : (rowB0 + brow - BM);
        srcp[j] = sbase + (size_t)grow * DIM + sc * 8;
    }
    ushort* dst0 = &lds[w * 8 * 512];
    ushort* dst1 = dst0 + PHASE_USH;

    f32x4 acc[4][4];
    #pragma unroll
    for (int m = 0; m < 4; ++m)
        #pragma unroll
        for (int n = 0; n < 4; ++n)
            acc[m][n] = (f32x4){0.f, 0.f, 0.f, 0.f};

    auto STAGE = [&](int kt, ushort* dwave) {
        #pragma unroll
        for (int j = 0; j < 8; ++j)
            GLLDS(srcp[j] + kt * BKE, dwave + j * 512);
    };
    auto COMPUTE = [&](const ushort* base) {
        bf16x8 Ah[4], Al[4], Bh[4], Bl[4];
        #pragma unroll
        for (int m = 0; m < 4; ++m) {
            int r = wr * 64 + m * 16 + l15;
            const ushort* rp = base + r * ROW_USH;
            Ah[m] = *(const bf16x8*)(rp + ((l4 ^ (r & 7)) << 3));
            Al[m] = *(const bf16x8*)(rp + (((l4 | 4) ^ (r & 7)) << 3));
        }
        #pragma unroll
        for (int n = 0; n < 4; ++n) {
            int r = wc * 64 + n * 16 + l15;
            const ushort* rp = base + (BM + r) * ROW_USH;
            Bh[n] = *(const bf16x8*)(rp + ((l4 ^ (r & 7)) << 3));
            Bl[n] = *(const bf16x8*)(rp + (((l4 | 4) ^ (r & 7)) << 3));
        }
        #pragma unroll
        for (int m = 0; m < 4; ++m)
            #pragma unroll
            for (int n = 0; n < 4; ++n) {
                acc[m][n] = __builtin_amdgcn_mfma_f32_16x16x32_bf16(Ah[m], Bh[n], acc[m][n], 0, 0, 0);
                acc[m][n] = __builtin_amdgcn_mfma_f32_16x16x32_bf16(Ah[m], Bl[n], acc[m][n], 0, 0, 0);
                acc[m][n] = __builtin_amdgcn_mfma_f32_16x16x32_bf16(Al[m], Bh[n], acc[m][n], 0, 0, 0);
            }
    };

    STAGE(0, dst0);
    __syncthreads();                    // implicit vmcnt(0): phase0 ready
    for (int kt2 = 0; kt2 < KSTEPS / 2; ++kt2) {
        int kt = kt2 * 2;
        STAGE(kt + 1, dst1);            // issue-early: hides under compute
        COMPUTE(lds);                   // phase 0
        __syncthreads();
        if (kt + 2 < KSTEPS) STAGE(kt + 2, dst0);
        COMPUTE(lds + PHASE_USH);       // phase 1
        __syncthreads();
    }

    // Epilogue. C/D layout (m89-verified): col = lane&15, row = (lane>>4)*4 + reg.
    float cmin[4], sqb_[4];
    #pragma unroll
    for (int n = 0; n < 4; ++n) {
        cmin[n] = FLTMAX;
        sqb_[n] = sq[rowB0 + wc * 64 + n * 16 + l15];
    }
    #pragma unroll
    for (int m = 0; m < 4; ++m) {
        #pragma unroll
        for (int r = 0; r < 4; ++r) {
            int gi = rowA0 + wr * 64 + m * 16 + l4 * 4 + r;
            float sa = sq[gi];
            float rm = FLTMAX;
            #pragma unroll
            for (int n = 0; n < 4; ++n) {
                int gj = rowB0 + wc * 64 + n * 16 + l15;
                float d2 = sa + sqb_[n] - 2.0f * acc[m][n][r];
                d2 = fmaxf(d2, 0.0f);                              // keep uint ordering
                if (((gi - gj) & (NHALF - 1)) == 0) d2 = FLTMAX;   // same label / diag
                rm = fminf(rm, d2);
                cmin[n] = fminf(cmin[n], d2);
            }
            rm = fminf(rm, __shfl_xor(rm, 1));
            rm = fminf(rm, __shfl_xor(rm, 2));
            rm = fminf(rm, __shfl_xor(rm, 4));
            rm = fminf(rm, __shfl_xor(rm, 8));
            if (l15 == 0) atomicMin(&minb[gi], __float_as_uint(rm));
        }
    }
    #pragma unroll
    for (int n = 0; n < 4; ++n) {
        cmin[n] = fminf(cmin[n], __shfl_xor(cmin[n], 16));
        cmin[n] = fminf(cmin[n], __shfl_xor(cmin[n], 32));
    }
    if (l4 == 0) {
        #pragma unroll
        for (int n = 0; n < 4; ++n)
            atomicMin(&minb[rowB0 + wc * 64 + n * 16 + l15], __float_as_uint(cmin[n]));
    }

    // Last-block-done finalize.
    __syncthreads();                      // all atomics of this block issued+drained
    if (tid == 0) {
        __threadfence();
        finflag = atomicAdd(cnt, 1u);
    }
    __syncthreads();
    if (finflag != NTRI - 1) return;

    float* red = (float*)lds;             // reuse LDS: [5][256]
    float sum_diff = 0.f, sum_rel = 0.f, sum_sq = 0.f, cnt_rel = 0.f, cnt_good = 0.f;
    for (int i = tid; i < NTOT; i += 256) {
        unsigned int mb = atomicOr(&minb[i], 0u);   // coherent read
        float hn = fmaxf(sqrtf(fmaxf(__uint_as_float(mb), 1e-14f)), 1e-7f);
        float hp = fmaxf(sqrtf(fmaxf(hp_d2[i], 1e-14f)), 1e-7f);
        float diff = hp - hn;
        float tt = fmaxf(diff + 0.1f, 0.0f);
        sum_diff += diff;
        sum_sq += sq[i];
        if (tt < 1e-5f) cnt_good += 1.0f;
        if (tt > 1e-5f) { cnt_rel += 1.0f; sum_rel += tt; }
    }
    red[0 * 256 + tid] = sum_diff; red[1 * 256 + tid] = sum_rel;
    red[2 * 256 + tid] = sum_sq;   red[3 * 256 + tid] = cnt_rel;
    red[4 * 256 + tid] = cnt_good;
    __syncthreads();
    for (int s = 128; s > 0; s >>= 1) {
        if (tid < s) {
            #pragma unroll
            for (int q = 0; q < 5; ++q) red[q * 256 + tid] += red[q * 256 + tid + s];
        }
        __syncthreads();
    }
    if (tid == 0) {
        float nrel = fmaxf(red[3 * 256], 1.0f);
        out[0] = red[1 * 256] / nrel;              // loss
        out[1] = red[0 * 256] / (float)NTOT;       // mean(differences)
        out[2] = red[4 * 256];                     // good
        out[3] = (float)NTOT - red[4 * 256];       // bad
        out[4] = sqrtf(red[2 * 256] / (float)NTOT);// sqrt(mean norm^2)
    }
}

extern "C" void kernel_launch(void* const* d_in, const int* in_sizes, int n_in,
                              void* d_out, int out_size, void* d_ws, size_t ws_size,
                              hipStream_t stream) {
    const float* h1 = (const float*)d_in[0];
    const float* h2 = (const float*)d_in[1];
    // d_in[2] (h3) unused by the reference.

    char* ws = (char*)d_ws;
    float* sq = (float*)ws;                               // 16 KB
    float* hp_d2 = (float*)(ws + 16384);                  // 16 KB
    unsigned int* minb = (unsigned int*)(ws + 32768);     // 16 KB
    unsigned int* cnt = (unsigned int*)(ws + 49152);      // 4 B (16 KB slot)
    ushort* hi = (ushort*)(ws + 65536);                   // 4 MB
    ushort* lo = hi + (size_t)NTOT * DIM;                 // 4 MB
    float* out = (float*)d_out;

    prep_kernel<<<NHALF / 4, 256, 0, stream>>>(h1, h2, sq, hp_d2, minb, cnt, hi, lo);
    pairmin_mfma<<<NTRI, 256, 0, stream>>>(hi, lo, sq, hp_d2, minb, cnt, out);
}